// Round 5
// baseline (137.103 us; speedup 1.0000x reference)
//
#include <hip/hip_runtime.h>
#include <hip/hip_bf16.h>

// BlurDownsample: depthwise 4x4 FIR (separable taps [1,3,3,1]/8 per axis),
// stride-2 downsample, pad (1,1). x: [N,C,256,256] f32 -> y: [N,C,128,128] f32.
//
// R5: vertical-first separable order. Vertical FIR combines 4 input rows as
// float4 in-lane (no exchange), THEN one horizontal FIR on the combined
// vector -> 2 shuffles + 1 lgkm wait per output row (was 4 + 2). Clamped rows
// peeled out of the main loop (only wave 0's first row and wave 3's last row
// touch the pad), so the 31-iter main loop is pure load/shfl/fma/store.
//  - wave-per-row float4 loads (1KB coalesced per row per wave)
//  - __launch_bounds__(256, 8): 8 waves/SIMD resident
//  - rolling 4-register vertical window (2 new rows per output row)
//  - nontemporal float2 stores (streaming output)

constexpr int H  = 256;
constexpr int W  = 256;
constexpr int OH = 128;
constexpr int OW = 128;
constexpr int WAVES_PER_BLOCK = 4;           // 256 threads
constexpr int TILE = OH / WAVES_PER_BLOCK;   // 32 output rows per wave

typedef float f32x2 __attribute__((ext_vector_type(2)));

__global__ __launch_bounds__(256, 8) void blur_down_kernel(
    const float* __restrict__ x, float* __restrict__ y) {
    const int plane = blockIdx.x;
    const int wave  = threadIdx.x >> 6;
    const int lane  = threadIdx.x & 63;

    const float* __restrict__ xp = x + (size_t)plane * H * W + lane * 4;
    float* __restrict__ yp       = y + (size_t)plane * OH * OW + 2 * lane;

    const int oh0 = wave * TILE;             // first output row of this wave
    const int r0  = 2 * oh0 - 1;             // first input row of the window

    const float mL = (lane == 0)  ? 0.0f : 1.0f;  // col -1 zero pad
    const float mR = (lane == 63) ? 0.0f : 1.0f;  // col 256 zero pad

    auto load_row = [&](int r) -> float4 {
        return *reinterpret_cast<const float4*>(xp + (size_t)r * W);
    };
    // clamped+masked load for the two possible out-of-range rows
    auto load_row_m = [&](int r) -> float4 {
        const int rc  = min(max(r, 0), H - 1);
        const float m = (r == rc) ? 1.0f : 0.0f;
        float4 v = load_row(rc);
        v.x *= m; v.y *= m; v.z *= m; v.w *= m;
        return v;
    };

    // one output row from the 4-row window a0..a3
    auto emit = [&](int k, const float4& a0, const float4& a1,
                    const float4& a2, const float4& a3) {
        float4 v;   // vertical FIR: (a0+a3) + 3*(a1+a2), per column, in-lane
        v.x = (a0.x + a3.x) + 3.0f * (a1.x + a2.x);
        v.y = (a0.y + a3.y) + 3.0f * (a1.y + a2.y);
        v.z = (a0.z + a3.z) + 3.0f * (a1.z + a2.z);
        v.w = (a0.w + a3.w) + 3.0f * (a1.w + a2.w);
        const float vm1 = __shfl_up(v.w, 1) * mL;   // col 4t-1
        const float vp4 = __shfl_down(v.x, 1) * mR; // col 4t+4
        f32x2 out;  // horizontal FIR + 1/64 normalization
        out.x = ((vm1 + v.z) + 3.0f * (v.x + v.y)) * (1.0f / 64.0f);
        out.y = ((v.y + vp4) + 3.0f * (v.z + v.w)) * (1.0f / 64.0f);
        __builtin_nontemporal_store(
            out, reinterpret_cast<f32x2*>(yp + (size_t)(oh0 + k) * OW));
    };

    // prologue: row r0 clamps only for wave 0; row r0+1 is always in range
    float4 a0 = load_row_m(r0);
    float4 a1 = load_row(r0 + 1);

    // main loop: rows r0+2 .. r0+63 are always in [1, 253] -> no masking
    #pragma unroll 4
    for (int k = 0; k < TILE - 1; ++k) {
        float4 a2 = load_row(r0 + 2 * k + 2);
        float4 a3 = load_row(r0 + 2 * k + 3);
        emit(k, a0, a1, a2, a3);
        a0 = a2; a1 = a3;
    }
    // epilogue: last row (r0+65 = 2*oh0+64) is 256 for wave 3 -> masked
    {
        const int k = TILE - 1;
        float4 a2 = load_row(r0 + 2 * k + 2);     // <= 255, in range
        float4 a3 = load_row_m(r0 + 2 * k + 3);
        emit(k, a0, a1, a2, a3);
    }
}

extern "C" void kernel_launch(void* const* d_in, const int* in_sizes, int n_in,
                              void* d_out, int out_size, void* d_ws, size_t ws_size,
                              hipStream_t stream) {
    const float* x = (const float*)d_in[0];
    float* y = (float*)d_out;

    const int planes = in_sizes[0] / (H * W);   // N*C = 2048
    hipLaunchKernelGGL(blur_down_kernel, dim3(planes), dim3(256), 0, stream,
                       x, y);
}

// Round 6
// 123.461 us; speedup vs baseline: 1.1105x; 1.1105x over previous
//
#include <hip/hip_runtime.h>
#include <hip/hip_bf16.h>

// BlurDownsample: depthwise 4x4 FIR (separable taps [1,3,3,1]/8 per axis),
// stride-2 downsample, pad (1,1). x: [N,C,256,256] f32 -> y: [N,C,128,128] f32.
//
// R6 = R4 structure (horizontal-first FIR; fastest so far at 130.9us), plus:
//  - #pragma unroll 8: 16 loads in flight between vmcnt drain points (was 8)
//  - nontemporal loads for the streaming x reads (read-once, evict-first)
// Kept from R4:
//  - wave-per-row float4 loads + shfl neighbor exchange (2 shfl per h-row)
//  - __launch_bounds__(256, 8): 8 waves/SIMD resident
//  - branch-free row padding (clamped row index + uniform 0/1 mask)
//  - rolling 4-scalar h-window (h0e,h0o,h1e,h1o), 2 new h-rows per output row
//  - nontemporal float2 stores

constexpr int H  = 256;
constexpr int W  = 256;
constexpr int OH = 128;
constexpr int OW = 128;
constexpr int WAVES_PER_BLOCK = 4;           // 256 threads
constexpr int TILE = OH / WAVES_PER_BLOCK;   // 32 output rows per wave

typedef float f32x2 __attribute__((ext_vector_type(2)));
typedef float f32x4 __attribute__((ext_vector_type(4)));

__global__ __launch_bounds__(256, 8) void blur_down_kernel(
    const float* __restrict__ x, float* __restrict__ y) {
    const int plane = blockIdx.x;
    const int wave  = threadIdx.x >> 6;
    const int lane  = threadIdx.x & 63;

    const float* __restrict__ xp = x + (size_t)plane * H * W + lane * 4;
    float* __restrict__ yp       = y + (size_t)plane * OH * OW + 2 * lane;

    const int oh0 = wave * TILE;             // first output row of this wave
    const int r0  = 2 * oh0 - 1;             // first input row of the window

    const float mL = (lane == 0)  ? 0.0f : 1.0f;  // col -1 zero pad
    const float mR = (lane == 63) ? 0.0f : 1.0f;  // col 256 zero pad

    // horizontal FIR on an already-loaded row vector
    // he (ow=2t)   = x[4t-1] + 3x[4t]   + 3x[4t+1] + x[4t+2]
    // ho (ow=2t+1) = x[4t+1] + 3x[4t+2] + 3x[4t+3] + x[4t+4]
    auto hfir = [&](const f32x4& v, float& he, float& ho) {
        const float xm1 = __shfl_up(v.w, 1) * mL;   // col 4t-1
        const float xp4 = __shfl_down(v.x, 1) * mR; // col 4t+4
        he = (xm1 + v.z) + 3.0f * (v.x + v.y);
        ho = (v.y + xp4) + 3.0f * (v.z + v.w);
    };

    // main-loop h-row: unconditional nontemporal load (rows always in range)
    auto hrow_nt = [&](int r, float& he, float& ho) {
        const f32x4 v = __builtin_nontemporal_load(
            reinterpret_cast<const f32x4*>(xp + (size_t)r * W));
        hfir(v, he, ho);
    };
    // edge h-row: clamped row index + uniform 0/1 mask, regular load
    auto hrow_m = [&](int r, float& he, float& ho) {
        const int rc  = min(max(r, 0), H - 1);
        const float m = (r == rc) ? 1.0f : 0.0f;
        const f32x4 v = *reinterpret_cast<const f32x4*>(xp + (size_t)rc * W);
        hfir(v, he, ho);
        he *= m; ho *= m;
    };

    // prologue: row r0 clamps only for wave 0; row r0+1 always in range
    float h0e, h0o, h1e, h1o;
    hrow_m(r0, h0e, h0o);
    hrow_nt(r0 + 1, h1e, h1o);

    // main loop: rows r0+2 .. r0+63 are in [1, 253] -> unconditional
    #pragma unroll 8
    for (int k = 0; k < TILE - 1; ++k) {
        float h2e, h2o, h3e, h3o;
        hrow_nt(r0 + 2 * k + 2, h2e, h2o);
        hrow_nt(r0 + 2 * k + 3, h3e, h3o);
        f32x2 out;
        out.x = ((h0e + h3e) + 3.0f * (h1e + h2e)) * (1.0f / 64.0f);
        out.y = ((h0o + h3o) + 3.0f * (h1o + h2o)) * (1.0f / 64.0f);
        __builtin_nontemporal_store(
            out, reinterpret_cast<f32x2*>(yp + (size_t)(oh0 + k) * OW));
        h0e = h2e; h0o = h2o;
        h1e = h3e; h1o = h3o;
    }
    // epilogue: last row (r0+65) is 256 for wave 3 -> masked
    {
        const int k = TILE - 1;
        float h2e, h2o, h3e, h3o;
        hrow_nt(r0 + 2 * k + 2, h2e, h2o);       // row <= 255, in range
        hrow_m(r0 + 2 * k + 3, h3e, h3o);
        f32x2 out;
        out.x = ((h0e + h3e) + 3.0f * (h1e + h2e)) * (1.0f / 64.0f);
        out.y = ((h0o + h3o) + 3.0f * (h1o + h2o)) * (1.0f / 64.0f);
        __builtin_nontemporal_store(
            out, reinterpret_cast<f32x2*>(yp + (size_t)(oh0 + k) * OW));
    }
}

extern "C" void kernel_launch(void* const* d_in, const int* in_sizes, int n_in,
                              void* d_out, int out_size, void* d_ws, size_t ws_size,
                              hipStream_t stream) {
    const float* x = (const float*)d_in[0];
    float* y = (float*)d_out;

    const int planes = in_sizes[0] / (H * W);   // N*C = 2048
    hipLaunchKernelGGL(blur_down_kernel, dim3(planes), dim3(256), 0, stream,
                       x, y);
}

// Round 7
// 120.989 us; speedup vs baseline: 1.1332x; 1.0204x over previous
//
#include <hip/hip_runtime.h>
#include <hip/hip_bf16.h>

// BlurDownsample: depthwise 4x4 FIR (separable taps [1,3,3,1]/8 per axis),
// stride-2 downsample, pad (1,1). x: [N,C,256,256] f32 -> y: [N,C,128,128] f32.
//
// R7 = R6 with __launch_bounds__(256, 6) instead of (256, 8).
// Rationale: (256,8) caps VGPR at 64, but the unroll-8 body needs 64 VGPRs
// for the 16 in-flight float4 load destinations alone -> compiler must
// recycle registers and insert mid-body vmcnt waits, throttling per-wave MLP.
// 6 waves/SIMD (24/CU) still gives ample TLP; ~85 VGPRs lets the load train
// stay outstanding.
//  - wave-per-row float4 loads + shfl neighbor exchange (2 shfl per h-row)
//  - branch-free row padding (clamped row index + uniform 0/1 mask)
//  - rolling 4-scalar h-window, 2 new h-rows per output row
//  - #pragma unroll 8, nontemporal loads + stores

constexpr int H  = 256;
constexpr int W  = 256;
constexpr int OH = 128;
constexpr int OW = 128;
constexpr int WAVES_PER_BLOCK = 4;           // 256 threads
constexpr int TILE = OH / WAVES_PER_BLOCK;   // 32 output rows per wave

typedef float f32x2 __attribute__((ext_vector_type(2)));
typedef float f32x4 __attribute__((ext_vector_type(4)));

__global__ __launch_bounds__(256, 6) void blur_down_kernel(
    const float* __restrict__ x, float* __restrict__ y) {
    const int plane = blockIdx.x;
    const int wave  = threadIdx.x >> 6;
    const int lane  = threadIdx.x & 63;

    const float* __restrict__ xp = x + (size_t)plane * H * W + lane * 4;
    float* __restrict__ yp       = y + (size_t)plane * OH * OW + 2 * lane;

    const int oh0 = wave * TILE;             // first output row of this wave
    const int r0  = 2 * oh0 - 1;             // first input row of the window

    const float mL = (lane == 0)  ? 0.0f : 1.0f;  // col -1 zero pad
    const float mR = (lane == 63) ? 0.0f : 1.0f;  // col 256 zero pad

    // horizontal FIR on an already-loaded row vector
    // he (ow=2t)   = x[4t-1] + 3x[4t]   + 3x[4t+1] + x[4t+2]
    // ho (ow=2t+1) = x[4t+1] + 3x[4t+2] + 3x[4t+3] + x[4t+4]
    auto hfir = [&](const f32x4& v, float& he, float& ho) {
        const float xm1 = __shfl_up(v.w, 1) * mL;   // col 4t-1
        const float xp4 = __shfl_down(v.x, 1) * mR; // col 4t+4
        he = (xm1 + v.z) + 3.0f * (v.x + v.y);
        ho = (v.y + xp4) + 3.0f * (v.z + v.w);
    };

    // main-loop h-row: unconditional nontemporal load (rows always in range)
    auto hrow_nt = [&](int r, float& he, float& ho) {
        const f32x4 v = __builtin_nontemporal_load(
            reinterpret_cast<const f32x4*>(xp + (size_t)r * W));
        hfir(v, he, ho);
    };
    // edge h-row: clamped row index + uniform 0/1 mask, regular load
    auto hrow_m = [&](int r, float& he, float& ho) {
        const int rc  = min(max(r, 0), H - 1);
        const float m = (r == rc) ? 1.0f : 0.0f;
        const f32x4 v = *reinterpret_cast<const f32x4*>(xp + (size_t)rc * W);
        hfir(v, he, ho);
        he *= m; ho *= m;
    };

    // prologue: row r0 clamps only for wave 0; row r0+1 always in range
    float h0e, h0o, h1e, h1o;
    hrow_m(r0, h0e, h0o);
    hrow_nt(r0 + 1, h1e, h1o);

    // main loop: rows r0+2 .. r0+63 are in [1, 253] -> unconditional
    #pragma unroll 8
    for (int k = 0; k < TILE - 1; ++k) {
        float h2e, h2o, h3e, h3o;
        hrow_nt(r0 + 2 * k + 2, h2e, h2o);
        hrow_nt(r0 + 2 * k + 3, h3e, h3o);
        f32x2 out;
        out.x = ((h0e + h3e) + 3.0f * (h1e + h2e)) * (1.0f / 64.0f);
        out.y = ((h0o + h3o) + 3.0f * (h1o + h2o)) * (1.0f / 64.0f);
        __builtin_nontemporal_store(
            out, reinterpret_cast<f32x2*>(yp + (size_t)(oh0 + k) * OW));
        h0e = h2e; h0o = h2o;
        h1e = h3e; h1o = h3o;
    }
    // epilogue: last row (r0+65) is 256 for wave 3 -> masked
    {
        const int k = TILE - 1;
        float h2e, h2o, h3e, h3o;
        hrow_nt(r0 + 2 * k + 2, h2e, h2o);       // row <= 255, in range
        hrow_m(r0 + 2 * k + 3, h3e, h3o);
        f32x2 out;
        out.x = ((h0e + h3e) + 3.0f * (h1e + h2e)) * (1.0f / 64.0f);
        out.y = ((h0o + h3o) + 3.0f * (h1o + h2o)) * (1.0f / 64.0f);
        __builtin_nontemporal_store(
            out, reinterpret_cast<f32x2*>(yp + (size_t)(oh0 + k) * OW));
    }
}

extern "C" void kernel_launch(void* const* d_in, const int* in_sizes, int n_in,
                              void* d_out, int out_size, void* d_ws, size_t ws_size,
                              hipStream_t stream) {
    const float* x = (const float*)d_in[0];
    float* y = (float*)d_out;

    const int planes = in_sizes[0] / (H * W);   // N*C = 2048
    hipLaunchKernelGGL(blur_down_kernel, dim3(planes), dim3(256), 0, stream,
                       x, y);
}